// Round 20
// baseline (527.310 us; speedup 1.0000x reference)
//
#include <hip/hip_runtime.h>
#include <math.h>

typedef _Float16 f16;
typedef __attribute__((ext_vector_type(8))) _Float16 f16x8;
typedef __attribute__((ext_vector_type(4))) _Float16 f16x4;
typedef __attribute__((ext_vector_type(2))) _Float16 f16x2;
typedef __attribute__((ext_vector_type(4))) float f32x4;
typedef __attribute__((ext_vector_type(2))) float f32x2;

#define NB 4
#define NT 20000
#define NN 60000
#define HD 128

#define MFMA(a,b,c) __builtin_amdgcn_mfma_f32_16x16x32_f16((a),(b),(c),0,0,0)

// tanh-form GELU: x*sigmoid(2*sqrt(2/pi)*(x+0.044715x^3)); |err vs erf-gelu| < 4e-4
__device__ __forceinline__ float gelu_f(float x){
    const float x2 = x*x;
    const float z  = x*(1.5957691216f + 0.0713548162726f*x2);  // 2*sqrt(2/pi)*(x+0.044715x^3)
    const float t  = __builtin_amdgcn_exp2f(-1.442695041f*z);  // e^{-z} via exp2
    return x * __builtin_amdgcn_rcpf(1.0f + t);
}

// ---------- fused pack: all 8 weights -> f16 MFMA B-frag order
struct PackArgs {
    const float* src[8];
    int K[8], Nc[8], off[8];
};
__global__ __launch_bounds__(256) void k_pack_all(PackArgs pa, f16* __restrict__ dst){
    int e = blockIdx.x*256 + threadIdx.x;
    if (e >= 245760) return;
    int s = 0;
#pragma unroll
    for (int i=1;i<8;i++) if (e >= pa.off[i]) s = i;
    const int el = e - pa.off[s];
    const int Nc = pa.Nc[s];
    const float* src = pa.src[s];
    int j = el & 7;
    int lane = (el>>3) & 63;
    int tile = el >> 9;
    int nct = Nc >> 4;
    int ct = tile % nct;
    int kb = tile / nct;
    int k = kb*32 + ((lane>>4)<<3) + j;
    int n = ct*16 + (lane&15);
    dst[e] = (f16)src[k*Nc + n];
}

// ---------------- k_inflate7 (r19 — unchanged)
__global__ __launch_bounds__(256) void k_inflate7(
    const float* __restrict__ hexf, const float* __restrict__ vertf,
    const int* __restrict__ v2h, const f16* __restrict__ BPinf,
    const float* __restrict__ b_inf, f16* __restrict__ v1h)
{
    __shared__ float Vst[4*2112];
    const int tid = threadIdx.x;
    const int wave = tid>>6, lane = tid&63;
    const int l15 = lane&15, kg = lane>>4;
    float* Vf = Vst + wave*2112;
    const long tile0 = (long)(blockIdx.x*4 + wave)*16;
    const int b = (int)(tile0 / NN);
    const int n = (int)(tile0 - (long)b*NN) + l15;
    const long hbase = (long)b*NT;
    int idx[3];
#pragma unroll
    for (int s=0;s<3;s++) idx[s] = v2h[n*3+s];

#pragma unroll
    for (int r=0;r<16;r++){
        f32x2 v = *(const f32x2*)(vertf + (tile0+r)*HD + lane*2);
        Vf[r*132 + lane*2]   = v[0];
        Vf[r*132 + lane*2+1] = v[1];
    }

    f32x4 acc[8];
#pragma unroll
    for (int i=0;i<8;i++) acc[i]=(f32x4){0.f,0.f,0.f,0.f};

#pragma unroll
    for (int slot=0; slot<3; slot++){
        const int id = idx[slot];
        f16x8 af[4];
        if (id>=0){
            const float* p = hexf + ((hbase+id)*HD + kg*8);
            f32x4 x0[4], x1[4];
#pragma unroll
            for (int c=0;c<4;c++){
                x0[c] = *(const f32x4*)(p + c*32);
                x1[c] = *(const f32x4*)(p + c*32 + 4);
            }
#pragma unroll
            for (int c=0;c<4;c++){
#pragma unroll
                for (int j=0;j<4;j++){ af[c][j]=(f16)x0[c][j]; af[c][4+j]=(f16)x1[c][j]; }
            }
        } else {
#pragma unroll
            for (int c=0;c<4;c++) af[c]=(f16x8){0,0,0,0,0,0,0,0};
        }
#pragma unroll
        for (int c=0;c<4;c++){
            const int kb = slot*4+c;
#pragma unroll
            for (int ct=0;ct<8;ct++){
                f16x8 bf = *(const f16x8*)(BPinf + (((kb*8+ct)*64+lane)<<3));
                acc[ct]=MFMA(af[c],bf,acc[ct]);
            }
        }
    }
#pragma unroll
    for (int ct=0; ct<8; ct++){
        const int col = ct*16 + l15;
        const float bi = b_inf[col];
#pragma unroll
        for (int r=0;r<4;r++){
            const int rl = kg*4+r;
            const long row = tile0 + rl;
            v1h[row*HD + col] = (f16)(acc[ct][r] + bi + Vf[rl*132 + col]);
        }
    }
}

// ---------------- k_vertex6 (r18 winner; only gelu_f body changed)
__global__ __launch_bounds__(256,4) void k_vertex6(
    const f16* __restrict__ v1h, const int* __restrict__ vadj,
    const f16* __restrict__ BPmsg, const float* __restrict__ b_msg,
    const f16* __restrict__ BPupd, const float* __restrict__ b_upd,
    const float* __restrict__ vng, const float* __restrict__ vnb,
    const f16* __restrict__ BPv1, const float* __restrict__ bv1,
    const f16* __restrict__ BPv2, const float* __restrict__ bv2,
    float* __restrict__ vout)
{
    __shared__ f16 lds[4*4352];
    __shared__ float ics[4*16];
    const int tid=threadIdx.x, wave=tid>>6, lane=tid&63;
    const int l15=lane&15, kg=lane>>4;
    f16* R0 = lds + wave*4352;
    f16* R1 = R0 + 2176;
    float* scr = (float*)R1;
    float* IC = ics + wave*16;
    const long tile0 = (long)(blockIdx.x*4+wave)*16;
    const int b = (int)(tile0 / NN);
    const int n0 = (int)(tile0 - (long)b*NN);
    const long gbase = (long)b*NN;

    // s1: quarter-wave gathering — 16B loads
#pragma unroll
    for (int rb=0; rb<16; rb+=4){
        const int r = rb + kg;
        const int n = n0 + r;
        f16x8 own = *(const f16x8*)(v1h + (tile0+r)*HD + l15*8);
        float s[8];
#pragma unroll
        for (int k=0;k<8;k++) s[k]=0.f;
        int cnt=0;
#pragma unroll
        for (int j=0;j<3;j++){
            const int idx = vadj[n*3+j];
            if (idx>=0){
                cnt++;
                f16x8 p = *(const f16x8*)(v1h + (gbase+idx)*HD + l15*8);
#pragma unroll
                for (int k=0;k<8;k++) s[k] += (float)p[k];
            }
        }
        f16x8 sv;
#pragma unroll
        for (int k=0;k<8;k++) sv[k]=(f16)s[k];
        *(f16x8*)(R0 + r*136 + l15*8) = sv;
        *(f16x8*)(R1 + r*136 + l15*8) = own;
        if (l15==0) IC[r] = 1.0f/(float)(cnt<1?1:cnt);
    }

    f32x4 acc[8];
    // s2: agg = (s @ W_msg + 3*b_msg)/cnt -> R0
#pragma unroll
    for (int i=0;i<8;i++) acc[i]=(f32x4){0.f,0.f,0.f,0.f};
#pragma unroll
    for (int kb=0;kb<4;kb++){
        f16x8 af = *(const f16x8*)(R0 + l15*136 + kb*32 + kg*8);
#pragma unroll
        for (int ct=0;ct<8;ct++){
            f16x8 bf = *(const f16x8*)(BPmsg + (((kb*8+ct)*64+lane)<<3));
            acc[ct]=MFMA(af,bf,acc[ct]);
        }
    }
#pragma unroll
    for (int ct=0;ct<8;ct++){
        const int col = ct*16+l15;
        const float bm = 3.0f*b_msg[col];
#pragma unroll
        for (int r=0;r<4;r++){
            const int rl = kg*4+r;
            R0[rl*136 + col] = (f16)((acc[ct][r]+bm)*IC[rl]);
        }
    }

    // s4: u = [own(R1), agg(R0)] @ W_upd -> acc ; += b_upd + residual(R1)
#pragma unroll
    for (int i=0;i<8;i++) acc[i]=(f32x4){0.f,0.f,0.f,0.f};
#pragma unroll
    for (int kb=0;kb<8;kb++){
        f16x8 af;
        if (kb<4) af = *(const f16x8*)(R1 + l15*136 + kb*32 + kg*8);
        else      af = *(const f16x8*)(R0 + l15*136 + (kb-4)*32 + kg*8);
#pragma unroll
        for (int ct=0;ct<8;ct++){
            f16x8 bf = *(const f16x8*)(BPupd + (((kb*8+ct)*64+lane)<<3));
            acc[ct]=MFMA(af,bf,acc[ct]);
        }
    }
#pragma unroll
    for (int ct=0;ct<8;ct++){
        const int col=ct*16+l15;
        const float bu = b_upd[col];
#pragma unroll
        for (int r=0;r<4;r++)
            acc[ct][r] += bu + (float)R1[(kg*4+r)*136 + col];
    }
    // LN via scratch @R1 (own dead)
    float mu_r[4], rs_r[4];
    {
#pragma unroll
        for (int r=0;r<4;r++){
            float ps=0.f;
#pragma unroll
            for (int ct=0;ct<8;ct++) ps += acc[ct][r];
            scr[(kg*4+r)*16 + l15] = ps;
        }
        if (lane<16){
            float s=0.f;
#pragma unroll
            for (int i=0;i<4;i++){
                f32x4 v = *(const f32x4*)(scr + lane*16 + i*4);
                s += (v[0]+v[1])+(v[2]+v[3]);
            }
            scr[256+lane] = s*(1.f/HD);
        }
#pragma unroll
        for (int r=0;r<4;r++) mu_r[r] = scr[256+kg*4+r];
#pragma unroll
        for (int r=0;r<4;r++){
            float pq=0.f;
#pragma unroll
            for (int ct=0;ct<8;ct++){ const float d=acc[ct][r]-mu_r[r]; pq += d*d; }
            scr[(kg*4+r)*16 + l15] = pq;
        }
        if (lane<16){
            float s=0.f;
#pragma unroll
            for (int i=0;i<4;i++){
                f32x4 v = *(const f32x4*)(scr + lane*16 + i*4);
                s += (v[0]+v[1])+(v[2]+v[3]);
            }
            scr[272+lane] = rsqrtf(s*(1.f/HD)+1e-5f);
        }
#pragma unroll
        for (int r=0;r<4;r++) rs_r[r] = scr[272+kg*4+r];
    }
    // x -> R0 (agg dead)
#pragma unroll
    for (int ct=0;ct<8;ct++){
        const int col=ct*16+l15;
        const float g = vng[col], bb = vnb[col];
#pragma unroll
        for (int r=0;r<4;r++){
            const int rl=kg*4+r;
            R0[rl*136 + col] = (f16)((acc[ct][r]-mu_r[r])*rs_r[r]*g + bb);
        }
    }

    // MLP h-half split
    f32x4 acc_y[8];
#pragma unroll
    for (int i=0;i<8;i++) acc_y[i]=(f32x4){0.f,0.f,0.f,0.f};
#pragma unroll
    for (int half=0; half<2; half++){
#pragma unroll
        for (int i=0;i<8;i++) acc[i]=(f32x4){0.f,0.f,0.f,0.f};
#pragma unroll
        for (int kb=0;kb<4;kb++){
            f16x8 af = *(const f16x8*)(R0 + l15*136 + kb*32 + kg*8);
#pragma unroll
            for (int ct=0;ct<8;ct++){
                const int ctp = half*8+ct;
                f16x8 bf = *(const f16x8*)(BPv1 + (((kb*16+ctp)*64+lane)<<3));
                acc[ct]=MFMA(af,bf,acc[ct]);
            }
        }
#pragma unroll
        for (int ct=0;ct<8;ct++){
            const int colg = half*128 + ct*16 + l15;
            const float bb = bv1[colg];
#pragma unroll
            for (int r=0;r<4;r++){
                const int rl=kg*4+r;
                R1[rl*136 + ct*16+l15] = (f16)gelu_f(acc[ct][r]+bb);
            }
        }
#pragma unroll
        for (int kb=0;kb<4;kb++){
            f16x8 af = *(const f16x8*)(R1 + l15*136 + kb*32 + kg*8);
#pragma unroll
            for (int ct=0;ct<8;ct++){
                f16x8 bf = *(const f16x8*)(BPv2 + ((((half*4+kb)*8+ct)*64+lane)<<3));
                acc_y[ct]=MFMA(af,bf,acc_y[ct]);
            }
        }
    }
    // y = x(R0) + acc_y + bv2 -> vout
#pragma unroll
    for (int ct=0;ct<8;ct++){
        const int col=ct*16+l15;
        const float bb=bv2[col];
#pragma unroll
        for (int r=0;r<4;r++){
            const int rl=kg*4+r;
            vout[(tile0+rl)*HD+col] = (float)R0[rl*136+col] + acc_y[ct][r] + bb;
        }
    }
}

// ---------------- k_hex6 (r18 winner; only gelu_f body changed)
__global__ __launch_bounds__(256,4) void k_hex6(
    const float* __restrict__ hexf, const float* __restrict__ vfin,
    const int* __restrict__ h2v,
    const f16* __restrict__ BPdef, const float* __restrict__ b_def,
    const float* __restrict__ hng, const float* __restrict__ hnb,
    const f16* __restrict__ BPh1, const float* __restrict__ bh1,
    const f16* __restrict__ BPh2, const float* __restrict__ bh2,
    float* __restrict__ hout)
{
    __shared__ f16 lds[4*4352];
    const int tid=threadIdx.x, wave=tid>>6, lane=tid&63;
    const int l15=lane&15, kg=lane>>4;
    f16* R0 = lds + wave*4352;
    f16* R1 = R0 + 2176;
    float* scr = (float*)R1;
    const long tile0 = (long)(blockIdx.x*4+wave)*16;
    const int b = (int)(tile0 / NT);
    const int t0 = (int)(tile0 - (long)b*NT);
    const long gbase = (long)b*NN;
    const int hh = lane>>5, c32 = lane&31;

    // s1: half-wave gathering (f32x4 loads)
#pragma unroll
    for (int rb=0; rb<16; rb+=2){
        const int r = rb + hh;
        const int t = t0 + r;
        f32x4 ow = *(const f32x4*)(hexf + (tile0+r)*HD + c32*4);
        float s[4] = {0.f,0.f,0.f,0.f};
        int cnt=0;
#pragma unroll
        for (int j=0;j<6;j++){
            const int idx = h2v[t*6+j];
            if (idx>=0){
                cnt++;
                f32x4 p = *(const f32x4*)(vfin + ((gbase+idx)*HD + c32*4));
#pragma unroll
                for (int k=0;k<4;k++) s[k] += p[k];
            }
        }
        const float ic = 1.0f/(float)(cnt<1?1:cnt);
        f16x4 sv, ov;
#pragma unroll
        for (int k=0;k<4;k++){ sv[k]=(f16)(s[k]*ic); ov[k]=(f16)ow[k]; }
        *(f16x4*)(R0 + r*136 + c32*4) = sv;
        *(f16x4*)(R1 + r*136 + c32*4) = ov;
    }

    f32x4 acc[8];
    // s2: deflated = p @ W_def -> acc ; += b_def + residual(R1)
#pragma unroll
    for (int i=0;i<8;i++) acc[i]=(f32x4){0.f,0.f,0.f,0.f};
#pragma unroll
    for (int kb=0;kb<4;kb++){
        f16x8 af = *(const f16x8*)(R0 + l15*136 + kb*32 + kg*8);
#pragma unroll
        for (int ct=0;ct<8;ct++){
            f16x8 bf = *(const f16x8*)(BPdef + (((kb*8+ct)*64+lane)<<3));
            acc[ct]=MFMA(af,bf,acc[ct]);
        }
    }
#pragma unroll
    for (int ct=0;ct<8;ct++){
        const int col=ct*16+l15;
        const float bd = b_def[col];
#pragma unroll
        for (int r=0;r<4;r++)
            acc[ct][r] += bd + (float)R1[(kg*4+r)*136 + col];
    }
    // LN via scratch @R1 (stage dead)
    float mu_r[4], rs_r[4];
    {
#pragma unroll
        for (int r=0;r<4;r++){
            float ps=0.f;
#pragma unroll
            for (int ct=0;ct<8;ct++) ps += acc[ct][r];
            scr[(kg*4+r)*16 + l15] = ps;
        }
        if (lane<16){
            float s=0.f;
#pragma unroll
            for (int i=0;i<4;i++){
                f32x4 v = *(const f32x4*)(scr + lane*16 + i*4);
                s += (v[0]+v[1])+(v[2]+v[3]);
            }
            scr[256+lane] = s*(1.f/HD);
        }
#pragma unroll
        for (int r=0;r<4;r++) mu_r[r] = scr[256+kg*4+r];
#pragma unroll
        for (int r=0;r<4;r++){
            float pq=0.f;
#pragma unroll
            for (int ct=0;ct<8;ct++){ const float d=acc[ct][r]-mu_r[r]; pq += d*d; }
            scr[(kg*4+r)*16 + l15] = pq;
        }
        if (lane<16){
            float s=0.f;
#pragma unroll
            for (int i=0;i<4;i++){
                f32x4 v = *(const f32x4*)(scr + lane*16 + i*4);
                s += (v[0]+v[1])+(v[2]+v[3]);
            }
            scr[272+lane] = rsqrtf(s*(1.f/HD)+1e-5f);
        }
#pragma unroll
        for (int r=0;r<4;r++) rs_r[r] = scr[272+kg*4+r];
    }
    // x -> R0 (p dead)
#pragma unroll
    for (int ct=0;ct<8;ct++){
        const int col=ct*16+l15;
        const float g = hng[col], bb = hnb[col];
#pragma unroll
        for (int r=0;r<4;r++){
            const int rl=kg*4+r;
            R0[rl*136 + col] = (f16)((acc[ct][r]-mu_r[r])*rs_r[r]*g + bb);
        }
    }

    // MLP h-half split
    f32x4 acc_y[8];
#pragma unroll
    for (int i=0;i<8;i++) acc_y[i]=(f32x4){0.f,0.f,0.f,0.f};
#pragma unroll
    for (int half=0; half<2; half++){
#pragma unroll
        for (int i=0;i<8;i++) acc[i]=(f32x4){0.f,0.f,0.f,0.f};
#pragma unroll
        for (int kb=0;kb<4;kb++){
            f16x8 af = *(const f16x8*)(R0 + l15*136 + kb*32 + kg*8);
#pragma unroll
            for (int ct=0;ct<8;ct++){
                const int ctp = half*8+ct;
                f16x8 bf = *(const f16x8*)(BPh1 + (((kb*16+ctp)*64+lane)<<3));
                acc[ct]=MFMA(af,bf,acc[ct]);
            }
        }
#pragma unroll
        for (int ct=0;ct<8;ct++){
            const int colg = half*128 + ct*16 + l15;
            const float bb = bh1[colg];
#pragma unroll
            for (int r=0;r<4;r++){
                const int rl=kg*4+r;
                R1[rl*136 + ct*16+l15] = (f16)gelu_f(acc[ct][r]+bb);
            }
        }
#pragma unroll
        for (int kb=0;kb<4;kb++){
            f16x8 af = *(const f16x8*)(R1 + l15*136 + kb*32 + kg*8);
#pragma unroll
            for (int ct=0;ct<8;ct++){
                f16x8 bf = *(const f16x8*)(BPh2 + ((((half*4+kb)*8+ct)*64+lane)<<3));
                acc_y[ct]=MFMA(af,bf,acc_y[ct]);
            }
        }
    }
#pragma unroll
    for (int ct=0;ct<8;ct++){
        const int col=ct*16+l15;
        const float bb=bh2[col];
#pragma unroll
        for (int r=0;r<4;r++){
            const int rl=kg*4+r;
            hout[(tile0+rl)*HD+col] = (float)R0[rl*136+col] + acc_y[ct][r] + bb;
        }
    }
}

extern "C" void kernel_launch(void* const* d_in, const int* in_sizes, int n_in,
                              void* d_out, int out_size, void* d_ws, size_t ws_size,
                              hipStream_t stream)
{
    (void)in_sizes; (void)n_in; (void)out_size; (void)ws_size;
    const float* hexf  = (const float*)d_in[0];
    const float* vertf = (const float*)d_in[1];
    const float* W_inf = (const float*)d_in[2];
    const float* b_inf = (const float*)d_in[3];
    const float* W_msg = (const float*)d_in[4];
    const float* b_msg = (const float*)d_in[5];
    const float* W_upd = (const float*)d_in[6];
    const float* b_upd = (const float*)d_in[7];
    const float* W_def = (const float*)d_in[8];
    const float* b_def = (const float*)d_in[9];
    const float* vng   = (const float*)d_in[10];
    const float* vnb   = (const float*)d_in[11];
    const float* hng   = (const float*)d_in[12];
    const float* hnb   = (const float*)d_in[13];
    const float* Wv1   = (const float*)d_in[14];
    const float* bv1   = (const float*)d_in[15];
    const float* Wv2   = (const float*)d_in[16];
    const float* bv2   = (const float*)d_in[17];
    const float* Wh1   = (const float*)d_in[18];
    const float* bh1   = (const float*)d_in[19];
    const float* Wh2   = (const float*)d_in[20];
    const float* bh2   = (const float*)d_in[21];
    const int* v2h   = (const int*)d_in[22];
    const int* h2v   = (const int*)d_in[23];
    const int* vadj  = (const int*)d_in[24];

    const long NV = (long)NB*NN;
    f16* v1h = (f16*)d_ws;                       // 61.44 MB
    f16* packs = (f16*)((char*)d_ws + (size_t)NV*HD*2);
    f16* BPinf = packs;
    f16* BPmsg = BPinf + 49152;
    f16* BPupd = BPmsg + 16384;
    f16* BPdef = BPupd + 32768;
    f16* BPv1  = BPdef + 16384;
    f16* BPv2  = BPv1 + 32768;
    f16* BPh1  = BPv2 + 32768;
    f16* BPh2  = BPh1 + 32768;

    PackArgs pa;
    pa.src[0]=W_inf; pa.K[0]=384; pa.Nc[0]=128; pa.off[0]=0;
    pa.src[1]=W_msg; pa.K[1]=128; pa.Nc[1]=128; pa.off[1]=49152;
    pa.src[2]=W_upd; pa.K[2]=256; pa.Nc[2]=128; pa.off[2]=65536;
    pa.src[3]=W_def; pa.K[3]=128; pa.Nc[3]=128; pa.off[3]=98304;
    pa.src[4]=Wv1;   pa.K[4]=128; pa.Nc[4]=256; pa.off[4]=114688;
    pa.src[5]=Wv2;   pa.K[5]=256; pa.Nc[5]=128; pa.off[5]=147456;
    pa.src[6]=Wh1;   pa.K[6]=128; pa.Nc[6]=256; pa.off[6]=180224;
    pa.src[7]=Wh2;   pa.K[7]=256; pa.Nc[7]=128; pa.off[7]=212992;
    k_pack_all<<<960,256,0,stream>>>(pa, packs);

    float* hout = (float*)d_out;
    float* vout = hout + (long)NB*NT*HD;

    k_inflate7<<<3750,256,0,stream>>>(hexf, vertf, v2h, BPinf, b_inf, v1h);
    k_vertex6<<<3750,256,0,stream>>>(v1h, vadj, BPmsg, b_msg, BPupd, b_upd,
                                     vng, vnb, BPv1, bv1, BPv2, bv2, vout);
    k_hex6<<<1250,256,0,stream>>>(hexf, vout, h2v, BPdef, b_def, hng, hnb,
                                  BPh1, bh1, BPh2, bh2, hout);
}

// Round 21
// 450.460 us; speedup vs baseline: 1.1706x; 1.1706x over previous
//
#include <hip/hip_runtime.h>
#include <math.h>

typedef _Float16 f16;
typedef __attribute__((ext_vector_type(8))) _Float16 f16x8;
typedef __attribute__((ext_vector_type(4))) _Float16 f16x4;
typedef __attribute__((ext_vector_type(2))) _Float16 f16x2;
typedef __attribute__((ext_vector_type(4))) float f32x4;
typedef __attribute__((ext_vector_type(2))) float f32x2;

#define NB 4
#define NT 20000
#define NN 60000
#define HD 128

#define MFMA(a,b,c) __builtin_amdgcn_mfma_f32_16x16x32_f16((a),(b),(c),0,0,0)

__device__ __forceinline__ float gelu_f(float t){
    return 0.5f*t*(1.0f+erff(t*0.70710678118654752f));
}

// ---------- fused pack: all 8 weights -> f16 MFMA B-frag order
struct PackArgs {
    const float* src[8];
    int K[8], Nc[8], off[8];
};
__global__ __launch_bounds__(256) void k_pack_all(PackArgs pa, f16* __restrict__ dst){
    int e = blockIdx.x*256 + threadIdx.x;
    if (e >= 245760) return;
    int s = 0;
#pragma unroll
    for (int i=1;i<8;i++) if (e >= pa.off[i]) s = i;
    const int el = e - pa.off[s];
    const int Nc = pa.Nc[s];
    const float* src = pa.src[s];
    int j = el & 7;
    int lane = (el>>3) & 63;
    int tile = el >> 9;
    int nct = Nc >> 4;
    int ct = tile % nct;
    int kb = tile / nct;
    int k = kb*32 + ((lane>>4)<<3) + j;
    int n = ct*16 + (lane&15);
    dst[e] = (f16)src[k*Nc + n];
}

// ---------------- k_inflate7: per-slot hoisted gather loads
__global__ __launch_bounds__(256) void k_inflate7(
    const float* __restrict__ hexf, const float* __restrict__ vertf,
    const int* __restrict__ v2h, const f16* __restrict__ BPinf,
    const float* __restrict__ b_inf, f16* __restrict__ v1h)
{
    __shared__ float Vst[4*2112];
    const int tid = threadIdx.x;
    const int wave = tid>>6, lane = tid&63;
    const int l15 = lane&15, kg = lane>>4;
    float* Vf = Vst + wave*2112;
    const long tile0 = (long)(blockIdx.x*4 + wave)*16;
    const int b = (int)(tile0 / NN);
    const int n = (int)(tile0 - (long)b*NN) + l15;
    const long hbase = (long)b*NT;
    int idx[3];
#pragma unroll
    for (int s=0;s<3;s++) idx[s] = v2h[n*3+s];

#pragma unroll
    for (int r=0;r<16;r++){
        f32x2 v = *(const f32x2*)(vertf + (tile0+r)*HD + lane*2);
        Vf[r*132 + lane*2]   = v[0];
        Vf[r*132 + lane*2+1] = v[1];
    }

    f32x4 acc[8];
#pragma unroll
    for (int i=0;i<8;i++) acc[i]=(f32x4){0.f,0.f,0.f,0.f};

#pragma unroll
    for (int slot=0; slot<3; slot++){
        const int id = idx[slot];
        f16x8 af[4];
        if (id>=0){
            const float* p = hexf + ((hbase+id)*HD + kg*8);
            f32x4 x0[4], x1[4];
#pragma unroll
            for (int c=0;c<4;c++){
                x0[c] = *(const f32x4*)(p + c*32);
                x1[c] = *(const f32x4*)(p + c*32 + 4);
            }
#pragma unroll
            for (int c=0;c<4;c++){
#pragma unroll
                for (int j=0;j<4;j++){ af[c][j]=(f16)x0[c][j]; af[c][4+j]=(f16)x1[c][j]; }
            }
        } else {
#pragma unroll
            for (int c=0;c<4;c++) af[c]=(f16x8){0,0,0,0,0,0,0,0};
        }
#pragma unroll
        for (int c=0;c<4;c++){
            const int kb = slot*4+c;
#pragma unroll
            for (int ct=0;ct<8;ct++){
                f16x8 bf = *(const f16x8*)(BPinf + (((kb*8+ct)*64+lane)<<3));
                acc[ct]=MFMA(af[c],bf,acc[ct]);
            }
        }
    }
#pragma unroll
    for (int ct=0; ct<8; ct++){
        const int col = ct*16 + l15;
        const float bi = b_inf[col];
#pragma unroll
        for (int r=0;r<4;r++){
            const int rl = kg*4+r;
            const long row = tile0 + rl;
            v1h[row*HD + col] = (f16)(acc[ct][r] + bi + Vf[rl*132 + col]);
        }
    }
}

// ---------------- k_vertex6 (r18/r19 winner — unchanged)
__global__ __launch_bounds__(256,4) void k_vertex6(
    const f16* __restrict__ v1h, const int* __restrict__ vadj,
    const f16* __restrict__ BPmsg, const float* __restrict__ b_msg,
    const f16* __restrict__ BPupd, const float* __restrict__ b_upd,
    const float* __restrict__ vng, const float* __restrict__ vnb,
    const f16* __restrict__ BPv1, const float* __restrict__ bv1,
    const f16* __restrict__ BPv2, const float* __restrict__ bv2,
    float* __restrict__ vout)
{
    __shared__ f16 lds[4*4352];
    __shared__ float ics[4*16];
    const int tid=threadIdx.x, wave=tid>>6, lane=tid&63;
    const int l15=lane&15, kg=lane>>4;
    f16* R0 = lds + wave*4352;
    f16* R1 = R0 + 2176;
    float* scr = (float*)R1;
    float* IC = ics + wave*16;
    const long tile0 = (long)(blockIdx.x*4+wave)*16;
    const int b = (int)(tile0 / NN);
    const int n0 = (int)(tile0 - (long)b*NN);
    const long gbase = (long)b*NN;

    // s1: quarter-wave gathering — 16B loads
#pragma unroll
    for (int rb=0; rb<16; rb+=4){
        const int r = rb + kg;
        const int n = n0 + r;
        f16x8 own = *(const f16x8*)(v1h + (tile0+r)*HD + l15*8);
        float s[8];
#pragma unroll
        for (int k=0;k<8;k++) s[k]=0.f;
        int cnt=0;
#pragma unroll
        for (int j=0;j<3;j++){
            const int idx = vadj[n*3+j];
            if (idx>=0){
                cnt++;
                f16x8 p = *(const f16x8*)(v1h + (gbase+idx)*HD + l15*8);
#pragma unroll
                for (int k=0;k<8;k++) s[k] += (float)p[k];
            }
        }
        f16x8 sv;
#pragma unroll
        for (int k=0;k<8;k++) sv[k]=(f16)s[k];
        *(f16x8*)(R0 + r*136 + l15*8) = sv;
        *(f16x8*)(R1 + r*136 + l15*8) = own;
        if (l15==0) IC[r] = 1.0f/(float)(cnt<1?1:cnt);
    }

    f32x4 acc[8];
    // s2: agg = (s @ W_msg + 3*b_msg)/cnt -> R0
#pragma unroll
    for (int i=0;i<8;i++) acc[i]=(f32x4){0.f,0.f,0.f,0.f};
#pragma unroll
    for (int kb=0;kb<4;kb++){
        f16x8 af = *(const f16x8*)(R0 + l15*136 + kb*32 + kg*8);
#pragma unroll
        for (int ct=0;ct<8;ct++){
            f16x8 bf = *(const f16x8*)(BPmsg + (((kb*8+ct)*64+lane)<<3));
            acc[ct]=MFMA(af,bf,acc[ct]);
        }
    }
#pragma unroll
    for (int ct=0;ct<8;ct++){
        const int col = ct*16+l15;
        const float bm = 3.0f*b_msg[col];
#pragma unroll
        for (int r=0;r<4;r++){
            const int rl = kg*4+r;
            R0[rl*136 + col] = (f16)((acc[ct][r]+bm)*IC[rl]);
        }
    }

    // s4: u = [own(R1), agg(R0)] @ W_upd -> acc ; += b_upd + residual(R1)
#pragma unroll
    for (int i=0;i<8;i++) acc[i]=(f32x4){0.f,0.f,0.f,0.f};
#pragma unroll
    for (int kb=0;kb<8;kb++){
        f16x8 af;
        if (kb<4) af = *(const f16x8*)(R1 + l15*136 + kb*32 + kg*8);
        else      af = *(const f16x8*)(R0 + l15*136 + (kb-4)*32 + kg*8);
#pragma unroll
        for (int ct=0;ct<8;ct++){
            f16x8 bf = *(const f16x8*)(BPupd + (((kb*8+ct)*64+lane)<<3));
            acc[ct]=MFMA(af,bf,acc[ct]);
        }
    }
#pragma unroll
    for (int ct=0;ct<8;ct++){
        const int col=ct*16+l15;
        const float bu = b_upd[col];
#pragma unroll
        for (int r=0;r<4;r++)
            acc[ct][r] += bu + (float)R1[(kg*4+r)*136 + col];
    }
    // LN via scratch @R1 (own dead)
    float mu_r[4], rs_r[4];
    {
#pragma unroll
        for (int r=0;r<4;r++){
            float ps=0.f;
#pragma unroll
            for (int ct=0;ct<8;ct++) ps += acc[ct][r];
            scr[(kg*4+r)*16 + l15] = ps;
        }
        if (lane<16){
            float s=0.f;
#pragma unroll
            for (int i=0;i<4;i++){
                f32x4 v = *(const f32x4*)(scr + lane*16 + i*4);
                s += (v[0]+v[1])+(v[2]+v[3]);
            }
            scr[256+lane] = s*(1.f/HD);
        }
#pragma unroll
        for (int r=0;r<4;r++) mu_r[r] = scr[256+kg*4+r];
#pragma unroll
        for (int r=0;r<4;r++){
            float pq=0.f;
#pragma unroll
            for (int ct=0;ct<8;ct++){ const float d=acc[ct][r]-mu_r[r]; pq += d*d; }
            scr[(kg*4+r)*16 + l15] = pq;
        }
        if (lane<16){
            float s=0.f;
#pragma unroll
            for (int i=0;i<4;i++){
                f32x4 v = *(const f32x4*)(scr + lane*16 + i*4);
                s += (v[0]+v[1])+(v[2]+v[3]);
            }
            scr[272+lane] = rsqrtf(s*(1.f/HD)+1e-5f);
        }
#pragma unroll
        for (int r=0;r<4;r++) rs_r[r] = scr[272+kg*4+r];
    }
    // x -> R0 (agg dead)
#pragma unroll
    for (int ct=0;ct<8;ct++){
        const int col=ct*16+l15;
        const float g = vng[col], bb = vnb[col];
#pragma unroll
        for (int r=0;r<4;r++){
            const int rl=kg*4+r;
            R0[rl*136 + col] = (f16)((acc[ct][r]-mu_r[r])*rs_r[r]*g + bb);
        }
    }

    // MLP h-half split
    f32x4 acc_y[8];
#pragma unroll
    for (int i=0;i<8;i++) acc_y[i]=(f32x4){0.f,0.f,0.f,0.f};
#pragma unroll
    for (int half=0; half<2; half++){
#pragma unroll
        for (int i=0;i<8;i++) acc[i]=(f32x4){0.f,0.f,0.f,0.f};
#pragma unroll
        for (int kb=0;kb<4;kb++){
            f16x8 af = *(const f16x8*)(R0 + l15*136 + kb*32 + kg*8);
#pragma unroll
            for (int ct=0;ct<8;ct++){
                const int ctp = half*8+ct;
                f16x8 bf = *(const f16x8*)(BPv1 + (((kb*16+ctp)*64+lane)<<3));
                acc[ct]=MFMA(af,bf,acc[ct]);
            }
        }
#pragma unroll
        for (int ct=0;ct<8;ct++){
            const int colg = half*128 + ct*16 + l15;
            const float bb = bv1[colg];
#pragma unroll
            for (int r=0;r<4;r++){
                const int rl=kg*4+r;
                R1[rl*136 + ct*16+l15] = (f16)gelu_f(acc[ct][r]+bb);
            }
        }
#pragma unroll
        for (int kb=0;kb<4;kb++){
            f16x8 af = *(const f16x8*)(R1 + l15*136 + kb*32 + kg*8);
#pragma unroll
            for (int ct=0;ct<8;ct++){
                f16x8 bf = *(const f16x8*)(BPv2 + ((((half*4+kb)*8+ct)*64+lane)<<3));
                acc_y[ct]=MFMA(af,bf,acc_y[ct]);
            }
        }
    }
    // y = x(R0) + acc_y + bv2 -> vout
#pragma unroll
    for (int ct=0;ct<8;ct++){
        const int col=ct*16+l15;
        const float bb=bv2[col];
#pragma unroll
        for (int r=0;r<4;r++){
            const int rl=kg*4+r;
            vout[(tile0+rl)*HD+col] = (float)R0[rl*136+col] + acc_y[ct][r] + bb;
        }
    }
}

// ---------------- k_hex6 (r18/r19 winner — unchanged)
__global__ __launch_bounds__(256,4) void k_hex6(
    const float* __restrict__ hexf, const float* __restrict__ vfin,
    const int* __restrict__ h2v,
    const f16* __restrict__ BPdef, const float* __restrict__ b_def,
    const float* __restrict__ hng, const float* __restrict__ hnb,
    const f16* __restrict__ BPh1, const float* __restrict__ bh1,
    const f16* __restrict__ BPh2, const float* __restrict__ bh2,
    float* __restrict__ hout)
{
    __shared__ f16 lds[4*4352];
    const int tid=threadIdx.x, wave=tid>>6, lane=tid&63;
    const int l15=lane&15, kg=lane>>4;
    f16* R0 = lds + wave*4352;
    f16* R1 = R0 + 2176;
    float* scr = (float*)R1;
    const long tile0 = (long)(blockIdx.x*4+wave)*16;
    const int b = (int)(tile0 / NT);
    const int t0 = (int)(tile0 - (long)b*NT);
    const long gbase = (long)b*NN;
    const int hh = lane>>5, c32 = lane&31;

    // s1: half-wave gathering (f32x4 loads)
#pragma unroll
    for (int rb=0; rb<16; rb+=2){
        const int r = rb + hh;
        const int t = t0 + r;
        f32x4 ow = *(const f32x4*)(hexf + (tile0+r)*HD + c32*4);
        float s[4] = {0.f,0.f,0.f,0.f};
        int cnt=0;
#pragma unroll
        for (int j=0;j<6;j++){
            const int idx = h2v[t*6+j];
            if (idx>=0){
                cnt++;
                f32x4 p = *(const f32x4*)(vfin + ((gbase+idx)*HD + c32*4));
#pragma unroll
                for (int k=0;k<4;k++) s[k] += p[k];
            }
        }
        const float ic = 1.0f/(float)(cnt<1?1:cnt);
        f16x4 sv, ov;
#pragma unroll
        for (int k=0;k<4;k++){ sv[k]=(f16)(s[k]*ic); ov[k]=(f16)ow[k]; }
        *(f16x4*)(R0 + r*136 + c32*4) = sv;
        *(f16x4*)(R1 + r*136 + c32*4) = ov;
    }

    f32x4 acc[8];
    // s2: deflated = p @ W_def -> acc ; += b_def + residual(R1)
#pragma unroll
    for (int i=0;i<8;i++) acc[i]=(f32x4){0.f,0.f,0.f,0.f};
#pragma unroll
    for (int kb=0;kb<4;kb++){
        f16x8 af = *(const f16x8*)(R0 + l15*136 + kb*32 + kg*8);
#pragma unroll
        for (int ct=0;ct<8;ct++){
            f16x8 bf = *(const f16x8*)(BPdef + (((kb*8+ct)*64+lane)<<3));
            acc[ct]=MFMA(af,bf,acc[ct]);
        }
    }
#pragma unroll
    for (int ct=0;ct<8;ct++){
        const int col=ct*16+l15;
        const float bd = b_def[col];
#pragma unroll
        for (int r=0;r<4;r++)
            acc[ct][r] += bd + (float)R1[(kg*4+r)*136 + col];
    }
    // LN via scratch @R1 (stage dead)
    float mu_r[4], rs_r[4];
    {
#pragma unroll
        for (int r=0;r<4;r++){
            float ps=0.f;
#pragma unroll
            for (int ct=0;ct<8;ct++) ps += acc[ct][r];
            scr[(kg*4+r)*16 + l15] = ps;
        }
        if (lane<16){
            float s=0.f;
#pragma unroll
            for (int i=0;i<4;i++){
                f32x4 v = *(const f32x4*)(scr + lane*16 + i*4);
                s += (v[0]+v[1])+(v[2]+v[3]);
            }
            scr[256+lane] = s*(1.f/HD);
        }
#pragma unroll
        for (int r=0;r<4;r++) mu_r[r] = scr[256+kg*4+r];
#pragma unroll
        for (int r=0;r<4;r++){
            float pq=0.f;
#pragma unroll
            for (int ct=0;ct<8;ct++){ const float d=acc[ct][r]-mu_r[r]; pq += d*d; }
            scr[(kg*4+r)*16 + l15] = pq;
        }
        if (lane<16){
            float s=0.f;
#pragma unroll
            for (int i=0;i<4;i++){
                f32x4 v = *(const f32x4*)(scr + lane*16 + i*4);
                s += (v[0]+v[1])+(v[2]+v[3]);
            }
            scr[272+lane] = rsqrtf(s*(1.f/HD)+1e-5f);
        }
#pragma unroll
        for (int r=0;r<4;r++) rs_r[r] = scr[272+kg*4+r];
    }
    // x -> R0 (p dead)
#pragma unroll
    for (int ct=0;ct<8;ct++){
        const int col=ct*16+l15;
        const float g = hng[col], bb = hnb[col];
#pragma unroll
        for (int r=0;r<4;r++){
            const int rl=kg*4+r;
            R0[rl*136 + col] = (f16)((acc[ct][r]-mu_r[r])*rs_r[r]*g + bb);
        }
    }

    // MLP h-half split
    f32x4 acc_y[8];
#pragma unroll
    for (int i=0;i<8;i++) acc_y[i]=(f32x4){0.f,0.f,0.f,0.f};
#pragma unroll
    for (int half=0; half<2; half++){
#pragma unroll
        for (int i=0;i<8;i++) acc[i]=(f32x4){0.f,0.f,0.f,0.f};
#pragma unroll
        for (int kb=0;kb<4;kb++){
            f16x8 af = *(const f16x8*)(R0 + l15*136 + kb*32 + kg*8);
#pragma unroll
            for (int ct=0;ct<8;ct++){
                const int ctp = half*8+ct;
                f16x8 bf = *(const f16x8*)(BPh1 + (((kb*16+ctp)*64+lane)<<3));
                acc[ct]=MFMA(af,bf,acc[ct]);
            }
        }
#pragma unroll
        for (int ct=0;ct<8;ct++){
            const int colg = half*128 + ct*16 + l15;
            const float bb = bh1[colg];
#pragma unroll
            for (int r=0;r<4;r++){
                const int rl=kg*4+r;
                R1[rl*136 + ct*16+l15] = (f16)gelu_f(acc[ct][r]+bb);
            }
        }
#pragma unroll
        for (int kb=0;kb<4;kb++){
            f16x8 af = *(const f16x8*)(R1 + l15*136 + kb*32 + kg*8);
#pragma unroll
            for (int ct=0;ct<8;ct++){
                f16x8 bf = *(const f16x8*)(BPh2 + ((((half*4+kb)*8+ct)*64+lane)<<3));
                acc_y[ct]=MFMA(af,bf,acc_y[ct]);
            }
        }
    }
#pragma unroll
    for (int ct=0;ct<8;ct++){
        const int col=ct*16+l15;
        const float bb=bh2[col];
#pragma unroll
        for (int r=0;r<4;r++){
            const int rl=kg*4+r;
            hout[(tile0+rl)*HD+col] = (float)R0[rl*136+col] + acc_y[ct][r] + bb;
        }
    }
}

extern "C" void kernel_launch(void* const* d_in, const int* in_sizes, int n_in,
                              void* d_out, int out_size, void* d_ws, size_t ws_size,
                              hipStream_t stream)
{
    (void)in_sizes; (void)n_in; (void)out_size; (void)ws_size;
    const float* hexf  = (const float*)d_in[0];
    const float* vertf = (const float*)d_in[1];
    const float* W_inf = (const float*)d_in[2];
    const float* b_inf = (const float*)d_in[3];
    const float* W_msg = (const float*)d_in[4];
    const float* b_msg = (const float*)d_in[5];
    const float* W_upd = (const float*)d_in[6];
    const float* b_upd = (const float*)d_in[7];
    const float* W_def = (const float*)d_in[8];
    const float* b_def = (const float*)d_in[9];
    const float* vng   = (const float*)d_in[10];
    const float* vnb   = (const float*)d_in[11];
    const float* hng   = (const float*)d_in[12];
    const float* hnb   = (const float*)d_in[13];
    const float* Wv1   = (const float*)d_in[14];
    const float* bv1   = (const float*)d_in[15];
    const float* Wv2   = (const float*)d_in[16];
    const float* bv2   = (const float*)d_in[17];
    const float* Wh1   = (const float*)d_in[18];
    const float* bh1   = (const float*)d_in[19];
    const float* Wh2   = (const float*)d_in[20];
    const float* bh2   = (const float*)d_in[21];
    const int* v2h   = (const int*)d_in[22];
    const int* h2v   = (const int*)d_in[23];
    const int* vadj  = (const int*)d_in[24];

    const long NV = (long)NB*NN;
    f16* v1h = (f16*)d_ws;                       // 61.44 MB
    f16* packs = (f16*)((char*)d_ws + (size_t)NV*HD*2);
    f16* BPinf = packs;
    f16* BPmsg = BPinf + 49152;
    f16* BPupd = BPmsg + 16384;
    f16* BPdef = BPupd + 32768;
    f16* BPv1  = BPdef + 16384;
    f16* BPv2  = BPv1 + 32768;
    f16* BPh1  = BPv2 + 32768;
    f16* BPh2  = BPh1 + 32768;

    PackArgs pa;
    pa.src[0]=W_inf; pa.K[0]=384; pa.Nc[0]=128; pa.off[0]=0;
    pa.src[1]=W_msg; pa.K[1]=128; pa.Nc[1]=128; pa.off[1]=49152;
    pa.src[2]=W_upd; pa.K[2]=256; pa.Nc[2]=128; pa.off[2]=65536;
    pa.src[3]=W_def; pa.K[3]=128; pa.Nc[3]=128; pa.off[3]=98304;
    pa.src[4]=Wv1;   pa.K[4]=128; pa.Nc[4]=256; pa.off[4]=114688;
    pa.src[5]=Wv2;   pa.K[5]=256; pa.Nc[5]=128; pa.off[5]=147456;
    pa.src[6]=Wh1;   pa.K[6]=128; pa.Nc[6]=256; pa.off[6]=180224;
    pa.src[7]=Wh2;   pa.K[7]=256; pa.Nc[7]=128; pa.off[7]=212992;
    k_pack_all<<<960,256,0,stream>>>(pa, packs);

    float* hout = (float*)d_out;
    float* vout = hout + (long)NB*NT*HD;

    k_inflate7<<<3750,256,0,stream>>>(hexf, vertf, v2h, BPinf, b_inf, v1h);
    k_vertex6<<<3750,256,0,stream>>>(v1h, vadj, BPmsg, b_msg, BPupd, b_upd,
                                     vng, vnb, BPv1, bv1, BPv2, bv2, vout);
    k_hex6<<<1250,256,0,stream>>>(hexf, vout, h2v, BPdef, b_def, hng, hnb,
                                  BPh1, bh1, BPh2, bh2, hout);
}